// Round 2
// baseline (323.714 us; speedup 1.0000x reference)
//
#include <hip/hip_runtime.h>
#include <hip/hip_bf16.h>
#include <stdint.h>

#define S 2048
#define D 64
#define BH 32                       // B*H
#define TILE 64                     // rows per block
#define NTHREADS 256                // 4 waves
#define KC 128                      // V k-chunk staged per barrier pair
#define VSTR 136                    // Vs row stride (bf16 elems; 272B, 16B-aligned)
#define CTX_ELEMS (BH * S * D)

typedef __attribute__((ext_vector_type(8))) __bf16 bf16x8;
typedef __attribute__((ext_vector_type(4))) float f32x4;
typedef __attribute__((ext_vector_type(4))) int   i32x4;

// One block = 64 rows of one (b,h). Phase 1: stream mask -> bit-matrix in LDS,
// row counts, write attn rows (mask?0:1/cnt). Phase 2: ctx = inv * bits @ V
// via bf16 MFMA 16x16x32 with V transposed-staged in LDS per 128-k chunk.
__global__ __launch_bounds__(NTHREADS) void k_fused(
    const int* __restrict__ mask, const float* __restrict__ V,
    float* __restrict__ ctx, float* __restrict__ attn) {

  const int qt = blockIdx.x;        // 0..31
  const int bh = blockIdx.y;        // 0..31
  const int t = threadIdx.x;
  const int lane = t & 63;
  const int w = t >> 6;             // wave 0..3
  const int l15 = lane & 15;
  const int lk = lane >> 4;         // 0..3

  __shared__ uint32_t pk[TILE][65];             // +1 pad: column reads conflict-free
  __shared__ float invs[TILE];
  __shared__ __align__(16) __bf16 Vs[64][VSTR]; // [col][k] transposed V chunk

  const long R0 = (long)bh * S + qt * TILE;     // first global row of this tile

  // ---------------- Phase 1: mask -> bits + counts + attn ----------------
  // wave w owns rows [w*16, w*16+16); one row processed by all 64 lanes,
  // 4 passes of 512 elems (8 per lane).
  for (int rr = 0; rr < 16; ++rr) {
    const int row = w * 16 + rr;
    const long R = R0 + row;
    const int* mrow = mask + R * (long)S;
    uint32_t bytes[4];
    int cnt = 0;
#pragma unroll
    for (int p = 0; p < 4; ++p) {
      const int base = p * 512 + lane * 8;
      i32x4 m0 = __builtin_nontemporal_load((const i32x4*)(mrow + base));
      i32x4 m1 = __builtin_nontemporal_load((const i32x4*)(mrow + base + 4));
      uint32_t b = 0;
      b |= (m0[0] == 0) ? 1u : 0u;
      b |= (m0[1] == 0) ? 2u : 0u;
      b |= (m0[2] == 0) ? 4u : 0u;
      b |= (m0[3] == 0) ? 8u : 0u;
      b |= (m1[0] == 0) ? 16u : 0u;
      b |= (m1[1] == 0) ? 32u : 0u;
      b |= (m1[2] == 0) ? 64u : 0u;
      b |= (m1[3] == 0) ? 128u : 0u;
      bytes[p] = b;
      cnt += __popc(b);
    }
#pragma unroll
    for (int off = 1; off < 64; off <<= 1) cnt += __shfl_xor(cnt, off, 64);
    const float inv = (cnt > 0) ? (1.0f / (float)cnt) : 0.0f;
    if (lane == 0) invs[row] = inv;

    // pack bytes -> 32-bit words: word widx covers k in [widx*32, widx*32+32)
#pragma unroll
    for (int p = 0; p < 4; ++p) {
      uint32_t wrd = ((uint32_t)__shfl((int)bytes[p], l15 * 4, 64) & 0xFFu)
                   | (((uint32_t)__shfl((int)bytes[p], l15 * 4 + 1, 64) & 0xFFu) << 8)
                   | (((uint32_t)__shfl((int)bytes[p], l15 * 4 + 2, 64) & 0xFFu) << 16)
                   | (((uint32_t)__shfl((int)bytes[p], l15 * 4 + 3, 64) & 0xFFu) << 24);
      if (lane < 16) pk[row][p * 16 + lane] = wrd;
    }

    float* arow = attn + R * (long)S;
#pragma unroll
    for (int p = 0; p < 4; ++p) {
      const uint32_t b = bytes[p];
      const int base = p * 512 + lane * 8;
      f32x4 a0, a1;
      a0[0] = (b & 1u)   ? inv : 0.0f;
      a0[1] = (b & 2u)   ? inv : 0.0f;
      a0[2] = (b & 4u)   ? inv : 0.0f;
      a0[3] = (b & 8u)   ? inv : 0.0f;
      a1[0] = (b & 16u)  ? inv : 0.0f;
      a1[1] = (b & 32u)  ? inv : 0.0f;
      a1[2] = (b & 64u)  ? inv : 0.0f;
      a1[3] = (b & 128u) ? inv : 0.0f;
      __builtin_nontemporal_store(a0, (f32x4*)(arow + base));
      __builtin_nontemporal_store(a1, (f32x4*)(arow + base + 4));
    }
  }
  __syncthreads();

  // ---------------- Phase 2: ctx = inv * (bits @ V) ----------------
  // wave w: M-tile rows [w*16, w*16+16), full N=64 (4 tiles of 16).
  f32x4 acc[4];
#pragma unroll
  for (int n4 = 0; n4 < 4; ++n4) acc[n4] = f32x4{0.f, 0.f, 0.f, 0.f};

  const int vcol = t & 63;
  const int vkg = (t >> 6) * 2;     // even k offset within group of 8

  for (int cb = 0; cb < S / KC; ++cb) {
    __syncthreads();                // previous chunk's reads done
    const float* vb = V + ((long)bh * S + cb * KC) * D;
#pragma unroll
    for (int j = 0; j < 16; ++j) {
      const int k2 = vkg + j * 8;   // even, 0..126
      const float f0 = vb[(long)k2 * D + vcol];
      const float f1 = vb[(long)(k2 + 1) * D + vcol];
      union { uint32_t u; __bf16 h[2]; } pr;
      pr.h[0] = (__bf16)f0;
      pr.h[1] = (__bf16)f1;
      *reinterpret_cast<uint32_t*>(&Vs[vcol][k2]) = pr.u;
    }
    __syncthreads();                // chunk staged

#pragma unroll
    for (int kk2 = 0; kk2 < 4; ++kk2) {   // 4 x K=32 within chunk
      const uint32_t dw = pk[w * 16 + l15][cb * 4 + kk2];
      const unsigned bby = (dw >> (lk * 8)) & 0xFFu;
      union { uint32_t u[4]; bf16x8 v; } au;
#pragma unroll
      for (int p = 0; p < 4; ++p) {
        uint32_t lo = ((bby >> (2 * p)) & 1u) ? 0x3F80u : 0u;
        uint32_t hi = ((bby >> (2 * p + 1)) & 1u) ? 0x3F800000u : 0u;
        au.u[p] = lo | hi;
      }
#pragma unroll
      for (int n4 = 0; n4 < 4; ++n4) {
        bf16x8 bf = *reinterpret_cast<const bf16x8*>(&Vs[n4 * 16 + l15][kk2 * 32 + lk * 8]);
        acc[n4] = __builtin_amdgcn_mfma_f32_16x16x32_bf16(au.v, bf, acc[n4], 0, 0, 0);
      }
    }
  }

  // epilogue: C/D layout col=l15, row=lk*4+ri (m89-verified)
#pragma unroll
  for (int ri = 0; ri < 4; ++ri) {
    const int rloc = w * 16 + lk * 4 + ri;
    const float iv = invs[rloc];
    const long orow = R0 + rloc;
#pragma unroll
    for (int n4 = 0; n4 < 4; ++n4) {
      ctx[orow * D + n4 * 16 + l15] = acc[n4][ri] * iv;
    }
  }
}

extern "C" void kernel_launch(void* const* d_in, const int* in_sizes, int n_in,
                              void* d_out, int out_size, void* d_ws, size_t ws_size,
                              hipStream_t stream) {
  (void)in_sizes; (void)n_in; (void)d_ws; (void)ws_size; (void)out_size;
  const float* V = (const float*)d_in[2];           // Q,K provably unused (mask overwrites all scores)
  const int* mask = (const int*)d_in[3];
  float* ctx = (float*)d_out;                       // output 0: [B,H,S,D]
  float* attn = (float*)d_out + (size_t)CTX_ELEMS;  // output 1: [B,H,S,S]

  k_fused<<<dim3(S / TILE, BH), NTHREADS, 0, stream>>>(mask, V, ctx, attn);
}

// Round 3
// 244.783 us; speedup vs baseline: 1.3225x; 1.3225x over previous
//
#include <hip/hip_runtime.h>
#include <hip/hip_bf16.h>
#include <stdint.h>

#define S 2048
#define D 64
#define BH 32                      // B*H
#define NROWS (BH * S)             // 65536
#define CTX_ELEMS (NROWS * D)

typedef __attribute__((ext_vector_type(8))) __bf16 bf16x8;
typedef __attribute__((ext_vector_type(4))) float f32x4;

// ---------- Kernel 1 (unchanged from R1 — proven ~BW-bound) ----------
// Per mask row: count unmasked, write attn row (mask?0:1/cnt), write bit-packed
// mask into the ctx region of d_out (k_ctx consumes then overwrites it).
__global__ __launch_bounds__(256) void k_mask(const int* __restrict__ mask,
                                              float* __restrict__ attn,
                                              uint32_t* packed) {
    const int r = blockIdx.x;           // row 0..65535
    const int t = threadIdx.x;          // 0..255, 8 elems each
    const long base = (long)r * S + t * 8;

    const int4 m0 = *(const int4*)(mask + base);
    const int4 m1 = *(const int4*)(mask + base + 4);
    int v[8] = {m0.x, m0.y, m0.z, m0.w, m1.x, m1.y, m1.z, m1.w};

    unsigned byte = 0;
    int cnt = 0;
#pragma unroll
    for (int j = 0; j < 8; ++j) {
        unsigned u = (v[j] == 0) ? 1u : 0u;   // 1 = unmasked
        byte |= u << j;
        cnt += (int)u;
    }
#pragma unroll
    for (int off = 32; off > 0; off >>= 1) cnt += __shfl_down(cnt, off, 64);

    __shared__ int wsum[4];
    __shared__ unsigned char bts[256];
    bts[t] = (unsigned char)byte;
    if ((t & 63) == 0) wsum[t >> 6] = cnt;
    __syncthreads();

    const int total = wsum[0] + wsum[1] + wsum[2] + wsum[3];
    const float inv = (total > 0) ? (1.0f / (float)total) : 0.0f;

    float4 a0, a1;
    a0.x = (byte & 1u)   ? inv : 0.0f;
    a0.y = (byte & 2u)   ? inv : 0.0f;
    a0.z = (byte & 4u)   ? inv : 0.0f;
    a0.w = (byte & 8u)   ? inv : 0.0f;
    a1.x = (byte & 16u)  ? inv : 0.0f;
    a1.y = (byte & 32u)  ? inv : 0.0f;
    a1.z = (byte & 64u)  ? inv : 0.0f;
    a1.w = (byte & 128u) ? inv : 0.0f;
    *(float4*)(attn + base)     = a0;
    *(float4*)(attn + base + 4) = a1;

    if (t < 64) {
        uint32_t w = (uint32_t)bts[4 * t]
                   | ((uint32_t)bts[4 * t + 1] << 8)
                   | ((uint32_t)bts[4 * t + 2] << 16)
                   | ((uint32_t)bts[4 * t + 3] << 24);
        packed[(long)r * 64 + t] = w;
    }
}

// ---------- Kernel 2 (rebuilt): ctx = inv * (bits @ V) ----------
// 128 rows/block, 4 waves, M=32/wave (2 M-tiles share B-frags). B-fragments
// read directly from global V (f32, L2-resident, line-coalesced), software-
// pipelined 2-deep. Packed bits in LDS bytes @ stride 260 (bank-conflict-free).
#define BMC 128
__global__ __launch_bounds__(256) void k_ctx(const uint32_t* __restrict__ packed,
                                             const float* __restrict__ V,
                                             float* __restrict__ ctx) {
    // XCD-aware swizzle: 512 wgs, 64/XCD -> each XCD owns 4 whole (b,h) (V in its L2)
    const int flat = blockIdx.y * (S / BMC) + blockIdx.x;
    const int wid = (flat & 7) * 64 + (flat >> 3);
    const int qt = wid & 15;            // row-tile within (b,h)
    const int bh = wid >> 4;

    const int t = threadIdx.x;
    const int lane = t & 63;
    const int w = t >> 6;               // wave 0..3
    const int l15 = lane & 15;
    const int lk = lane >> 4;           // 0..3

    __shared__ uint32_t pkw[BMC * 65];  // byte-view stride 260 -> bank stride 1
    __shared__ float invs[BMC];

    const long R0 = (long)bh * S + qt * BMC;

    // stage packed: 8192 words, coalesced global read, conflict-free LDS write
    for (int i = t; i < BMC * 64; i += 256) {
        pkw[(i >> 6) * 65 + (i & 63)] = packed[(R0 + (i >> 6)) * 64 + (i & 63)];
    }
    __syncthreads();

    if (t < BMC) {
        int c = 0;
#pragma unroll
        for (int i = 0; i < 64; ++i) c += __popc(pkw[t * 65 + i]);
        invs[t] = (c > 0) ? (1.0f / (float)c) : 0.0f;
    }
    __syncthreads();

    const uint8_t* pkb = (const uint8_t*)pkw;
    const uint8_t* aptr0 = pkb + (w * 32 + l15) * 260;        // mt=0 row
    const uint8_t* aptr1 = pkb + (w * 32 + 16 + l15) * 260;   // mt=1 row
    const float* vb = V + (long)bh * S * D + (long)lk * 8 * D + l15;

    f32x4 acc[2][4];
#pragma unroll
    for (int a = 0; a < 2; ++a)
#pragma unroll
        for (int b = 0; b < 4; ++b) acc[a][b] = f32x4{0.f, 0.f, 0.f, 0.f};

    float cur[32], nxt[32];

    auto LOADB = [&](float* dst, int kk) {
        const float* vp = vb + (long)kk * 32 * D;
#pragma unroll
        for (int n4 = 0; n4 < 4; ++n4)
#pragma unroll
            for (int j = 0; j < 8; ++j)
                dst[n4 * 8 + j] = vp[j * D + n4 * 16];
    };

    auto COMPUTE = [&](const float* buf, int kk) {
        bf16x8 bf[4];
#pragma unroll
        for (int n4 = 0; n4 < 4; ++n4) {
            bf16x8 x;
#pragma unroll
            for (int j = 0; j < 8; ++j) x[j] = (__bf16)buf[n4 * 8 + j];
            bf[n4] = x;
        }
        const uint32_t by0 = aptr0[kk * 4 + lk];
        const uint32_t by1 = aptr1[kk * 4 + lk];
        union { uint32_t u[4]; bf16x8 v; } a0, a1;
#pragma unroll
        for (int p = 0; p < 4; ++p) {
            a0.u[p] = (((by0 >> (2 * p)) & 1u) ? 0x3F80u : 0u)
                    | (((by0 >> (2 * p + 1)) & 1u) ? 0x3F800000u : 0u);
            a1.u[p] = (((by1 >> (2 * p)) & 1u) ? 0x3F80u : 0u)
                    | (((by1 >> (2 * p + 1)) & 1u) ? 0x3F800000u : 0u);
        }
#pragma unroll
        for (int n4 = 0; n4 < 4; ++n4) {
            acc[0][n4] = __builtin_amdgcn_mfma_f32_16x16x32_bf16(a0.v, bf[n4], acc[0][n4], 0, 0, 0);
            acc[1][n4] = __builtin_amdgcn_mfma_f32_16x16x32_bf16(a1.v, bf[n4], acc[1][n4], 0, 0, 0);
        }
    };

    LOADB(cur, 0);
    for (int kk = 0; kk < S / 32; kk += 2) {
        LOADB(nxt, kk + 1);
        COMPUTE(cur, kk);
        if (kk + 2 < S / 32) LOADB(cur, kk + 2);
        COMPUTE(nxt, kk + 1);
    }

    // epilogue: C/D layout col=l15, row=lk*4+ri (m89-verified)
#pragma unroll
    for (int mt = 0; mt < 2; ++mt) {
#pragma unroll
        for (int ri = 0; ri < 4; ++ri) {
            const int rloc = w * 32 + mt * 16 + lk * 4 + ri;
            const float iv = invs[rloc];
            const long orow = R0 + rloc;
#pragma unroll
            for (int n4 = 0; n4 < 4; ++n4) {
                ctx[orow * D + n4 * 16 + l15] = acc[mt][n4][ri] * iv;
            }
        }
    }
}

extern "C" void kernel_launch(void* const* d_in, const int* in_sizes, int n_in,
                              void* d_out, int out_size, void* d_ws, size_t ws_size,
                              hipStream_t stream) {
    (void)in_sizes; (void)n_in; (void)d_ws; (void)ws_size; (void)out_size;
    const float* V = (const float*)d_in[2];           // Q,K provably unused
    const int* mask = (const int*)d_in[3];
    float* ctx = (float*)d_out;                       // output 0: [B,H,S,D]
    float* attn = (float*)d_out + (size_t)CTX_ELEMS;  // output 1: [B,H,S,S]
    uint32_t* packed = (uint32_t*)d_out;              // scratch aliasing ctx region

    k_mask<<<NROWS, 256, 0, stream>>>(mask, attn, packed);
    k_ctx<<<dim3(S / BMC, BH), 256, 0, stream>>>(packed, V, ctx);
}